// Round 4
// baseline (522.395 us; speedup 1.0000x reference)
//
#include <hip/hip_runtime.h>
#include <math.h>

// Problem constants
#define BB   32
#define DD   512
#define NN   512
#define CC   512
#define HW   4096           // 64*64
#define NLOC (BB * HW)      // 131072 locations
#define NBD  (BB * DD)      // 16384 q outputs
#define NBC  (BB * CC)      // 16384 ct outputs

#define SCORE_WAVES 8192    // 2048 blocks * 4 waves
#define LPW (NLOC / SCORE_WAVES)   // 16 locations per wave (16 | 4096 -> same batch)

__device__ __forceinline__ float wave_reduce_sum(float v) {
#pragma unroll
    for (int m = 1; m < 64; m <<= 1) v += __shfl_xor(v, m, 64);
    return v;
}

__device__ __forceinline__ float dot4(float4 a, float4 b) {
    return a.x * b.x + a.y * b.y + a.z * b.z + a.w * b.w;
}

// Stable, branch-free tanh: 1 - 2/(e^{2x}+1). No NaN for any finite x.
__device__ __forceinline__ float tanh_fast(float x) {
    float t = __expf(2.0f * x);
    return 1.0f - 2.0f * __builtin_amdgcn_rcpf(t + 1.0f);
}

// ---------------- Kernel 1: q = ht_query @ Wq^T ----------------------------
// 1024 blocks * 256 threads; each wave computes 4 consecutive outputs
// (same b since 4 | 512), lane covers 8 consecutive n.
__global__ void qproj_kernel(const float* __restrict__ hq,
                             const float* __restrict__ Wq,
                             float* __restrict__ q) {
    int wid  = threadIdx.x >> 6;
    int lane = threadIdx.x & 63;
    int wave = blockIdx.x * 4 + wid;       // 0..4095
    int base = wave * 4;                   // 0..16380
    int b = base >> 9;
    const float* hrow = hq + (size_t)b * NN;
    float4 h0 = *(const float4*)(hrow + lane * 8);
    float4 h1 = *(const float4*)(hrow + lane * 8 + 4);
#pragma unroll
    for (int o = 0; o < 4; ++o) {
        int idx = base + o;
        int d = idx & 511;
        const float* wrow = Wq + (size_t)d * NN;
        float4 w0 = *(const float4*)(wrow + lane * 8);
        float4 w1 = *(const float4*)(wrow + lane * 8 + 4);
        float acc = dot4(h0, w0) + dot4(h1, w1);
        acc = wave_reduce_sum(acc);
        if (lane == 0) q[idx] = acc;
    }
}

// ---------------- Kernel 2: e = exp(score)*mask + per-wave denom partials --
// score[loc] = sum_d Wa[d]*tanh(key[loc,d] + q[b,d]) + ba.  No max-subtract:
// softmax is shift-invariant and |score| <= sum|Wa| ~ 18, exp safe in f32.
// 2048 blocks * 256; each wave owns 16 consecutive locations (same batch),
// preloading its q/Wa fragments once.
__global__ void score_exp_kernel(const float* __restrict__ key,
                                 const float* __restrict__ q,
                                 const float* __restrict__ Wa,
                                 const float* __restrict__ ba,
                                 const float* __restrict__ mask,
                                 float* __restrict__ ebuf,
                                 float* __restrict__ partials) {
    int wid  = threadIdx.x >> 6;
    int lane = threadIdx.x & 63;
    int gw   = blockIdx.x * 4 + wid;       // 0..8191
    int loc0 = gw * LPW;
    int b    = loc0 >> 12;                 // all 16 locs share b
    const float* qrow = q + (size_t)b * DD;
    float4 q0 = *(const float4*)(qrow + lane * 8);
    float4 q1 = *(const float4*)(qrow + lane * 8 + 4);
    float4 w0 = *(const float4*)(Wa + lane * 8);
    float4 w1 = *(const float4*)(Wa + lane * 8 + 4);
    float ba0 = ba[0];
    float part = 0.0f;
#pragma unroll 4
    for (int t = 0; t < LPW; ++t) {
        int loc = loc0 + t;
        const float* krow = key + (size_t)loc * DD;
        float4 k0 = *(const float4*)(krow + lane * 8);
        float4 k1 = *(const float4*)(krow + lane * 8 + 4);
        float acc;
        acc  = w0.x * tanh_fast(k0.x + q0.x);
        acc += w0.y * tanh_fast(k0.y + q0.y);
        acc += w0.z * tanh_fast(k0.z + q0.z);
        acc += w0.w * tanh_fast(k0.w + q0.w);
        acc += w1.x * tanh_fast(k1.x + q1.x);
        acc += w1.y * tanh_fast(k1.y + q1.y);
        acc += w1.z * tanh_fast(k1.z + q1.z);
        acc += w1.w * tanh_fast(k1.w + q1.w);
        acc = wave_reduce_sum(acc);
        if (lane == 0) {
            float e = __expf(acc + ba0) * mask[loc];
            ebuf[loc] = e;
            part += e;
        }
    }
    if (lane == 0) partials[gw] = part;
}

// ---------------- Kernel 3: per-batch denom + write normalized s_out -------
// 32 blocks (1 per batch) * 256 threads. partials per batch = 256 contiguous.
__global__ void denom_scale_kernel(const float* __restrict__ partials,
                                   const float* __restrict__ ebuf,
                                   float* __restrict__ inv_denom,
                                   float* __restrict__ s_out) {
    __shared__ float sm[4];
    int b = blockIdx.x;
    int wid = threadIdx.x >> 6, lane = threadIdx.x & 63;
    float p = partials[b * 256 + threadIdx.x];
    p = wave_reduce_sum(p);
    if (lane == 0) sm[wid] = p;
    __syncthreads();
    float total = sm[0] + sm[1] + sm[2] + sm[3];
    float inv = 1.0f / (total + 1e-10f);
    if (threadIdx.x == 0) inv_denom[b] = inv;
    const float* erow = ebuf + (size_t)b * HW;
    float* srow = s_out + (size_t)b * HW;
#pragma unroll
    for (int t = 0; t < 4; ++t) {
        int i = t * 1024 + threadIdx.x * 4;
        float4 e = *(const float4*)(erow + i);
        float4 r;
        r.x = e.x * inv; r.y = e.y * inv; r.z = e.z * inv; r.w = e.w * inv;
        *(float4*)(srow + i) = r;
    }
}

// ---------------- Kernel 4: ct[b,c] = inv_b * dot(val[b,c,:], e[b,:]) ------
// 2048 blocks * 256; each wave computes 2 consecutive (b,c) rows sharing the
// e-row loads (halves the hot-row traffic).
__global__ void ct_kernel(const float* __restrict__ val,
                          const float* __restrict__ ebuf,
                          const float* __restrict__ inv_denom,
                          float* __restrict__ ct) {
    int wid  = threadIdx.x >> 6;
    int lane = threadIdx.x & 63;
    int gw   = blockIdx.x * 4 + wid;       // 0..8191
    int idx0 = gw * 2;                     // 2 consecutive rows, same b
    int b = idx0 >> 9;
    float inv = inv_denom[b];
    const float* erow = ebuf + (size_t)b * HW;
    const float* v0 = val + (size_t)idx0 * HW;
    const float* v1 = v0 + HW;
    float acc0 = 0.0f, acc1 = 0.0f;
#pragma unroll 4
    for (int t = 0; t < 8; ++t) {
        int h = t * 512 + lane * 8;
        float4 e0 = *(const float4*)(erow + h);
        float4 e1 = *(const float4*)(erow + h + 4);
        float4 a0 = *(const float4*)(v0 + h);
        float4 a1 = *(const float4*)(v0 + h + 4);
        float4 c0 = *(const float4*)(v1 + h);
        float4 c1 = *(const float4*)(v1 + h + 4);
        acc0 += dot4(a0, e0) + dot4(a1, e1);
        acc1 += dot4(c0, e0) + dot4(c1, e1);
    }
    acc0 = wave_reduce_sum(acc0);
    acc1 = wave_reduce_sum(acc1);
    if (lane == 0) {
        ct[idx0]     = acc0 * inv;
        ct[idx0 + 1] = acc1 * inv;
    }
}

extern "C" void kernel_launch(void* const* d_in, const int* in_sizes, int n_in,
                              void* d_out, int out_size, void* d_ws, size_t ws_size,
                              hipStream_t stream) {
    const float* ctx_val  = (const float*)d_in[0];   // [B,C,H,W]
    const float* ctx_key  = (const float*)d_in[1];   // [B,H,W,D]
    const float* ctx_mask = (const float*)d_in[2];   // [B,H,W]
    const float* ht_query = (const float*)d_in[3];   // [B,N]
    const float* Wq       = (const float*)d_in[4];   // [D,N]
    const float* Wa       = (const float*)d_in[5];   // [1,D]
    const float* ba       = (const float*)d_in[6];   // [1]

    float* ct_out = (float*)d_out;                   // [B,C]
    float* s_out  = (float*)d_out + NBC;             // [B,H,W]

    float* ws       = (float*)d_ws;
    float* q        = ws;                            // 16384
    float* ebuf     = ws + NBD;                      // 131072
    float* partials = ws + NBD + NLOC;               // 8192
    float* invd     = ws + NBD + NLOC + SCORE_WAVES; // 32

    qproj_kernel<<<1024, 256, 0, stream>>>(ht_query, Wq, q);
    score_exp_kernel<<<2048, 256, 0, stream>>>(ctx_key, q, Wa, ba, ctx_mask,
                                               ebuf, partials);
    denom_scale_kernel<<<BB, 256, 0, stream>>>(partials, ebuf, invd, s_out);
    ct_kernel<<<2048, 256, 0, stream>>>(ctx_val, ebuf, invd, ct_out);
}